// Round 8
// baseline (709.742 us; speedup 1.0000x reference)
//
#include <hip/hip_runtime.h>

// NCC dual-force 3D, 256^3 fp32 — R9 ABLATION ROUND (resubmit; prior round
// was GPUAcquisitionTimeout, no data).
// R8 post-mortem: XCD swizzle cut FETCH 225->135MB with ZERO time change ->
// not fetch-bound. VALUBusy 48%, wall = VALU/0.48, per-wave idle ~88%.
// Three candidate stall theories; 3 rounds of guessing were ~neutral, so
// this round A/Bs them IN ONE RUN (4 dispatches, distinct kernel names):
//   1) ncc_k<8,false>  base (cold-eater)            ~121us expected
//   2) ncc_k<8,true>   halo-loads replace all 14 ds_bpermute/iter
//   3) ncc_k<16,false> CHUNK_Z=16 (priming 2/18 vs 2/10 of ingest work)
//   4) ncc_k<8,false>  base again -> FINAL OUTPUT (correctness guaranteed)
// bench dur_us will read ~4x (sacrificial); rocprof rows give per-variant
// timing via Kernel_Name. absmax must stay exactly 80 (variant 4 writes).

constexpr int DIM     = 256;
constexpr int PLANE   = DIM * DIM;
constexpr int NVOX    = DIM * DIM * DIM;
constexpr int BY      = 2;             // waves per block (y rows)
constexpr float EPSF  = 1e-6f;

constexpr int NBY   = DIM / BY;        // 128 y-blocks
constexpr int NXCD  = 8;

// native vector types for nontemporal builtins (HIP_vector_type is rejected)
typedef float nvec4 __attribute__((ext_vector_type(4)));
typedef int   nivec4 __attribute__((ext_vector_type(4)));

__device__ __forceinline__ float shlz(float v) {   // lane l <- lane l-1; lane0 -> 0 (zero pad)
    float r = __shfl_up(v, 1);
    return (threadIdx.x == 0) ? 0.f : r;
}
__device__ __forceinline__ float shrz(float v) {   // lane l <- lane l+1; lane63 -> 0
    float r = __shfl_down(v, 1);
    return (threadIdx.x == 63) ? 0.f : r;
}
__device__ __forceinline__ float4 add3(const float4& a, const float4& b, const float4& c) {
    return make_float4(a.x+b.x+c.x, a.y+b.y+c.y, a.z+b.z+c.z, a.w+b.w+c.w);
}
__device__ __forceinline__ float4 add2(const float4& a, const float4& b) {
    return make_float4(a.x+b.x, a.y+b.y, a.z+b.z, a.w+b.w);
}
__device__ __forceinline__ float4 prod3(const float4& a, const float4& b,
                                        const float4& c, const float4& d,
                                        const float4& e, const float4& f) {
    return make_float4(a.x*b.x + c.x*d.x + e.x*f.x,
                       a.y*b.y + c.y*d.y + e.y*f.y,
                       a.z*b.z + c.z*d.z + e.z*f.z,
                       a.w*b.w + c.w*d.w + e.w*f.w);
}
// scalar mirrors with IDENTICAL expression shape (same contraction decisions)
__device__ __forceinline__ float add3s(float a, float b, float c) { return a + b + c; }
__device__ __forceinline__ float prod3s(float a, float b, float c, float d, float e, float f) {
    return a*b + c*d + e*f;
}
__device__ __forceinline__ float4 sub4(const float4& a, const float4& b) {
    return make_float4(a.x-b.x, a.y-b.y, a.z-b.z, a.w-b.w);
}
__device__ __forceinline__ float4 scl4(const float4& a, float s) {
    return make_float4(a.x*s, a.y*s, a.z*s, a.w*s);
}
// 3-wide x window sum with explicit end values (l = value at xb-1, r = at xb+4)
__device__ __forceinline__ float4 xsum3h(const float4& c, float l, float r) {
    return make_float4(l + c.x + c.y, c.x + c.y + c.z, c.y + c.z + c.w, c.z + c.w + r);
}
__device__ __forceinline__ void ntstore4(float* p, const float4& v) {
    nvec4 t; t.x = v.x; t.y = v.y; t.z = v.z; t.w = v.w;
    __builtin_nontemporal_store(t, (nvec4*)p);
}

// scalar pointwise NCC-force; op-for-op identical to R1 (absmax 80 tripwire)
__device__ __forceinline__ void pw1(
    float sum_m, float sum_f, float sum_mm, float sum_ff, float sum_mf,
    float mA, float mB, float mN,
    float fA, float fB, float fN,
    int zflag,
    float gx_m, float gy_m, float gx_f, float gy_f,
    int km, int kf,
    float& o0, float& o1, float& o2)
{
    float mmean = sum_m / 27.0f;
    float fmean = sum_f / 27.0f;
    float var_m = sum_mm - 2.f*mmean*sum_m + 27.f*mmean*mmean;
    float var_f = sum_ff - 2.f*fmean*sum_f + 27.f*fmean*fmean;
    float var_mf = var_m * var_f;
    float cross = sum_mf - fmean*sum_m - mmean*sum_f + 27.f*mmean*fmean;
    float mmc = mB - mmean, fmc = fB - fmean;
    float factor = 2.f * cross / (var_mf + EPSF)
                   * (mmc - cross / (var_f*fmc + EPSF));
    float gzm = (zflag < 0) ? (mN - mB) : ((zflag > 0) ? (mB - mA) : 0.5f*(mN - mA));
    float gzf = (zflag < 0) ? (fN - fB) : ((zflag > 0) ? (fB - fA) : 0.5f*(fN - fA));
    float wm = km ? 1.f : 0.f, wf = kf ? 1.f : 0.f;
    float tgz = 0.5f*(gzm *wm + gzf *wf);
    float tgy = 0.5f*(gy_m*wm + gy_f*wf);
    float tgx = 0.5f*(gx_m*wm + gx_f*wf);
    o0 = -factor * tgz;
    o1 = -factor * tgy;
    o2 = -factor * tgx;
}

// raw rows of one z-plane for this wave's y (3 m-rows + 3 f-rows)
struct RawP { float4 mU, mC, mD, fU, fC, fD; };

__device__ __forceinline__ RawP load_planes(const float* __restrict__ M,
                                            const float* __restrict__ F,
                                            int zl, size_t yoff, bool yUok, bool yDok)
{
    const float4 z4 = make_float4(0.f, 0.f, 0.f, 0.f);
    RawP r; r.mU = z4; r.mC = z4; r.mD = z4; r.fU = z4; r.fC = z4; r.fD = z4;
    if ((unsigned)zl < (unsigned)DIM) {
        const float* pm = M + (size_t)zl * PLANE + yoff;
        const float* pf = F + (size_t)zl * PLANE + yoff;
        r.mC = *(const float4*)pm;  r.fC = *(const float4*)pf;
        if (yUok) { r.mU = *(const float4*)(pm - DIM); r.fU = *(const float4*)(pf - DIM); }
        if (yDok) { r.mD = *(const float4*)(pm + DIM); r.fD = *(const float4*)(pf + DIM); }
    }
    return r;
}

// compute half of the ingest. HALO=false: x-ends via __shfl (ds_bpermute).
// HALO=true: x-ends via 12 scalar halo loads (L1-hot: same lines as the
// float4 prefetch) + scalar re-derivation with bit-identical expressions.
template<bool HALO>
__device__ __forceinline__ void ingest_T(
    const float* __restrict__ M, const float* __restrict__ F,
    int zl, size_t yoff, bool yUok, bool yDok,
    const RawP& r, int slot, int y,
    float4* mc, float4* fc,
    float4& Pm, float4& Pf, float4& Pmm, float4& Pff, float4& Pmf,
    float4& gxm, float4& gym, float4& gxf, float4& gyf)
{
    const float4 mU = r.mU, mC = r.mC, mD = r.mD;
    const float4 fU = r.fU, fC = r.fC, fD = r.fD;
    // y-sums per element (zero-padded SAME)
    float4 Cm  = add3(mU, mC, mD);
    float4 Cf  = add3(fU, fC, fD);
    float4 Cmm = prod3(mU, mU, mC, mC, mD, mD);
    float4 Cff = prod3(fU, fU, fC, fC, fD, fD);
    float4 Cmf = prod3(mU, fU, mC, fC, mD, fD);

    float mL, mR, fL, fR;   // C-row x-neighbors (for in-plane x gradient)
    if constexpr (!HALO) {
        // x-sums via 2 shuffles per quantity
        Pm  = xsum3h(Cm,  shlz(Cm.w),  shrz(Cm.x));
        Pf  = xsum3h(Cf,  shlz(Cf.w),  shrz(Cf.x));
        Pmm = xsum3h(Cmm, shlz(Cmm.w), shrz(Cmm.x));
        Pff = xsum3h(Cff, shlz(Cff.w), shrz(Cff.x));
        Pmf = xsum3h(Cmf, shlz(Cmf.w), shrz(Cmf.x));
        mL = shlz(mC.w); mR = shrz(mC.x);
        fL = shlz(fC.w); fR = shrz(fC.x);
    } else {
        // halo loads: value at x = xb-1 (left) and xb+4 (right) of each row.
        // lane0 left / lane63 right are clamped in-bounds dummies, zeroed in
        // the derived values below (and unused by the gradient boundaries).
        float mUl=0.f,mUr=0.f,mCl=0.f,mCr=0.f,mDl=0.f,mDr=0.f;
        float fUl=0.f,fUr=0.f,fCl=0.f,fCr=0.f,fDl=0.f,fDr=0.f;
        if ((unsigned)zl < (unsigned)DIM) {
            const float* pm = M + (size_t)zl * PLANE + yoff;
            const float* pf = F + (size_t)zl * PLANE + yoff;
            const int offL = (threadIdx.x == 0)  ? 0 : -1;
            const int offR = (threadIdx.x == 63) ? 3 : 4;
            mCl = pm[offL]; mCr = pm[offR];
            fCl = pf[offL]; fCr = pf[offR];
            if (yUok) { mUl = pm[offL-DIM]; mUr = pm[offR-DIM];
                        fUl = pf[offL-DIM]; fUr = pf[offR-DIM]; }
            if (yDok) { mDl = pm[offL+DIM]; mDr = pm[offR+DIM];
                        fDl = pf[offL+DIM]; fDr = pf[offR+DIM]; }
        }
        // derived halo columns — identical expression shape to add3/prod3
        float CmLv  = add3s (mUl, mCl, mDl);
        float CfLv  = add3s (fUl, fCl, fDl);
        float CmmLv = prod3s(mUl, mUl, mCl, mCl, mDl, mDl);
        float CffLv = prod3s(fUl, fUl, fCl, fCl, fDl, fDl);
        float CmfLv = prod3s(mUl, fUl, mCl, fCl, mDl, fDl);
        float CmRv  = add3s (mUr, mCr, mDr);
        float CfRv  = add3s (fUr, fCr, fDr);
        float CmmRv = prod3s(mUr, mUr, mCr, mCr, mDr, mDr);
        float CffRv = prod3s(fUr, fUr, fCr, fCr, fDr, fDr);
        float CmfRv = prod3s(mUr, fUr, mCr, fCr, mDr, fDr);
        const bool l0 = (threadIdx.x == 0), l63 = (threadIdx.x == 63);
        CmLv  = l0 ? 0.f : CmLv;   CmRv  = l63 ? 0.f : CmRv;
        CfLv  = l0 ? 0.f : CfLv;   CfRv  = l63 ? 0.f : CfRv;
        CmmLv = l0 ? 0.f : CmmLv;  CmmRv = l63 ? 0.f : CmmRv;
        CffLv = l0 ? 0.f : CffLv;  CffRv = l63 ? 0.f : CffRv;
        CmfLv = l0 ? 0.f : CmfLv;  CmfRv = l63 ? 0.f : CmfRv;
        Pm  = xsum3h(Cm,  CmLv,  CmRv);
        Pf  = xsum3h(Cf,  CfLv,  CfRv);
        Pmm = xsum3h(Cmm, CmmLv, CmmRv);
        Pff = xsum3h(Cff, CffLv, CffRv);
        Pmf = xsum3h(Cmf, CmfLv, CmfRv);
        mL = mCl; mR = mCr; fL = fCl; fR = fCr;   // lane0/63 values unused below
    }

    mc[slot] = mC; fc[slot] = fC;
    // in-plane gradients at this plane (torch.gradient boundary rules)
    gxm = make_float4((threadIdx.x == 0)  ? (mC.y - mC.x) : 0.5f*(mC.y - mL),
                      0.5f*(mC.z - mC.x),
                      0.5f*(mC.w - mC.y),
                      (threadIdx.x == 63) ? (mC.w - mC.z) : 0.5f*(mR - mC.z));
    gxf = make_float4((threadIdx.x == 0)  ? (fC.y - fC.x) : 0.5f*(fC.y - fL),
                      0.5f*(fC.z - fC.x),
                      0.5f*(fC.w - fC.y),
                      (threadIdx.x == 63) ? (fC.w - fC.z) : 0.5f*(fR - fC.z));
    gym = (y == 0) ? sub4(mD, mC) : (y == DIM-1) ? sub4(mC, mU) : scl4(sub4(mD, mU), 0.5f);
    gyf = (y == 0) ? sub4(fD, fC) : (y == DIM-1) ? sub4(fC, fU) : scl4(sub4(fD, fU), 0.5f);
}

template<int CZ, bool HALO>
__global__ __launch_bounds__(64 * BY) void ncc_k(
    const float* __restrict__ M, const float* __restrict__ F,
    const int* __restrict__ maskM, const int* __restrict__ maskF,
    float* __restrict__ out)
{
    constexpr int NBZ_ = DIM / CZ;
    constexpr int NWG_ = NBY * NBZ_;
    constexpr int CHX_ = NWG_ / NXCD;       // blocks per XCD (bijective: NWG_%8==0)

    const int wg  = (int)blockIdx.x;
    const int swz = (wg & (NXCD - 1)) * CHX_ + (wg >> 3);
    const int by  = swz & (NBY - 1);        // y fastest within an XCD chunk
    const int bz  = swz >> 7;               // NBY == 128

    const int y  = by * BY + threadIdx.y;
    const int z0 = bz * CZ;
    const int xb = threadIdx.x * 4;
    const bool yUok = (y > 0), yDok = (y < DIM - 1);
    const size_t yoff = (size_t)y * DIM + xb;

    float4 mc[3], fc[3];
    float4 gxm_p, gym_p, gxf_p, gyf_p;

    // ---- prologue ----
    nivec4 km = __builtin_nontemporal_load((const nivec4*)(maskM + (size_t)z0 * PLANE + yoff));
    nivec4 kf = __builtin_nontemporal_load((const nivec4*)(maskF + (size_t)z0 * PLANE + yoff));
    RawP r0 = load_planes(M, F, z0 - 1, yoff, yUok, yDok);
    RawP r1 = load_planes(M, F, z0,     yoff, yUok, yDok);
    RawP rN = load_planes(M, F, z0 + 1, yoff, yUok, yDok);

    float4 SAm, SAf, SAmm, SAff, SAmf, SBm, SBf, SBmm, SBff, SBmf;
    {
        float4 P0m, P0f, P0mm, P0ff, P0mf, d0, d1, d2, d3;
        ingest_T<HALO>(M, F, z0 - 1, yoff, yUok, yDok, r0, 0, y, mc, fc,
                       P0m, P0f, P0mm, P0ff, P0mf, d0, d1, d2, d3);
        float4 P1m, P1f, P1mm, P1ff, P1mf;
        ingest_T<HALO>(M, F, z0, yoff, yUok, yDok, r1, 1, y, mc, fc,
                       P1m, P1f, P1mm, P1ff, P1mf, gxm_p, gym_p, gxf_p, gyf_p);
        SAm  = add2(P0m,  P1m );  SBm  = P1m;
        SAf  = add2(P0f,  P1f );  SBf  = P1f;
        SAmm = add2(P0mm, P1mm);  SBmm = P1mm;
        SAff = add2(P0ff, P1ff);  SBff = P1ff;
        SAmf = add2(P0mf, P1mf);  SBmf = P1mf;
    }

    #pragma unroll
    for (int s = 2; s < CZ + 2; ++s) {
        const int i2 = s % 3, i1 = (s + 2) % 3, i0 = (s + 1) % 3;
        const int zo = z0 + s - 2;
        const int zflag = (zo == 0) ? -1 : ((zo == DIM - 1) ? 1 : 0);
        const size_t idx = (size_t)zo * PLANE + yoff;

        float4 gxm, gym, gxf, gyf;
        float4 Pm2, Pf2, Pmm2, Pff2, Pmf2;
        ingest_T<HALO>(M, F, z0 - 1 + s, yoff, yUok, yDok, rN, i2, y, mc, fc,
                       Pm2, Pf2, Pmm2, Pff2, Pmf2, gxm, gym, gxf, gyf);

        nivec4 kmT, kfT;
        if (s < CZ + 1) {
            rN  = load_planes(M, F, z0 + s, yoff, yUok, yDok);
            kmT = __builtin_nontemporal_load((const nivec4*)(maskM + idx + PLANE));
            kfT = __builtin_nontemporal_load((const nivec4*)(maskF + idx + PLANE));
        }

        float4 sm  = add2(SAm,  Pm2);
        float4 sf  = add2(SAf,  Pf2);
        float4 smm = add2(SAmm, Pmm2);
        float4 sff = add2(SAff, Pff2);
        float4 smf = add2(SAmf, Pmf2);

        float4 o0, o1, o2;
        pw1(sm.x, sf.x, smm.x, sff.x, smf.x, mc[i0].x, mc[i1].x, mc[i2].x,
            fc[i0].x, fc[i1].x, fc[i2].x, zflag, gxm_p.x, gym_p.x, gxf_p.x, gyf_p.x,
            km.x, kf.x, o0.x, o1.x, o2.x);
        pw1(sm.y, sf.y, smm.y, sff.y, smf.y, mc[i0].y, mc[i1].y, mc[i2].y,
            fc[i0].y, fc[i1].y, fc[i2].y, zflag, gxm_p.y, gym_p.y, gxf_p.y, gyf_p.y,
            km.y, kf.y, o0.y, o1.y, o2.y);
        pw1(sm.z, sf.z, smm.z, sff.z, smf.z, mc[i0].z, mc[i1].z, mc[i2].z,
            fc[i0].z, fc[i1].z, fc[i2].z, zflag, gxm_p.z, gym_p.z, gxf_p.z, gyf_p.z,
            km.z, kf.z, o0.z, o1.z, o2.z);
        pw1(sm.w, sf.w, smm.w, sff.w, smf.w, mc[i0].w, mc[i1].w, mc[i2].w,
            fc[i0].w, fc[i1].w, fc[i2].w, zflag, gxm_p.w, gym_p.w, gxf_p.w, gyf_p.w,
            km.w, kf.w, o0.w, o1.w, o2.w);

        ntstore4(out + idx,            o0);
        ntstore4(out + NVOX + idx,     o1);
        ntstore4(out + 2 * NVOX + idx, o2);

        SAm  = add2(SBm,  Pm2 );  SBm  = Pm2;
        SAf  = add2(SBf,  Pf2 );  SBf  = Pf2;
        SAmm = add2(SBmm, Pmm2);  SBmm = Pmm2;
        SAff = add2(SBff, Pff2);  SBff = Pff2;
        SAmf = add2(SBmf, Pmf2);  SBmf = Pmf2;
        gxm_p = gxm; gym_p = gym; gxf_p = gxf; gyf_p = gyf;
        if (s < CZ + 1) { km = kmT; kf = kfT; }
    }
}

extern "C" void kernel_launch(void* const* d_in, const int* in_sizes, int n_in,
                              void* d_out, int out_size, void* d_ws, size_t ws_size,
                              hipStream_t stream) {
    const float* M  = (const float*)d_in[0];
    const float* F  = (const float*)d_in[1];
    const int* mm   = (const int*)d_in[2];
    const int* fm   = (const int*)d_in[3];
    float* out      = (float*)d_out;

    dim3 block(64, BY, 1);
    // ABLATION: 4 dispatches. Order matters:
    //   base (eats cold cache) -> noshuf -> chunk16 -> base (FINAL OUTPUT).
    hipLaunchKernelGGL((ncc_k<8,  false>), dim3(4096), block, 0, stream, M, F, mm, fm, out);
    hipLaunchKernelGGL((ncc_k<8,  true >), dim3(4096), block, 0, stream, M, F, mm, fm, out);
    hipLaunchKernelGGL((ncc_k<16, false>), dim3(2048), block, 0, stream, M, F, mm, fm, out);
    hipLaunchKernelGGL((ncc_k<8,  false>), dim3(4096), block, 0, stream, M, F, mm, fm, out);
}

// Round 9
// 385.825 us; speedup vs baseline: 1.8395x; 1.8395x over previous
//
#include <hip/hip_runtime.h>

// NCC dual-force 3D, 256^3 fp32.
// R10: PACKED-FP32 rewrite. Evidence chain: R8 swizzle cut FETCH 225->135MB
// with zero time change (not fetch-bound); R9 ablation: halo (-shuffles,
// +VALU) = 147us slower exactly by its added VALU at the SAME 50% busy;
// chunk16 neutral. Every experiment: wall ~= VALU-issue/0.50. Conclusion:
// VALU-issue-bound at a ~50% duty ceiling -> reduce issue count.
// CDNA fp32 peak needs v_pk_{add,mul,fma}_f32 (2-wide VOP3P); backend
// selects them from <2 x float>. All straight-line math now runs on v2f
// pairs (xy)/(zw) with TEXTUALLY IDENTICAL expression shapes (same
// contraction -> same bits; absmax must stay exactly 80). Divides stay
// scalarized (rcp+NR per element) — unavoidable. Structure (1-iter plane+
// mask prefetch, SA/SB pair-sum z-accum, XCD swizzle) unchanged from R8.
// Spill tripwire: WRITE_SIZE must stay ~197MB. VGPR target ~110.

constexpr int DIM     = 256;
constexpr int PLANE   = DIM * DIM;
constexpr int NVOX    = DIM * DIM * DIM;
constexpr int CHUNK_Z = 8;             // outputs per thread along z
constexpr int BY      = 2;             // waves per block (y rows)
constexpr float EPSF  = 1e-6f;

constexpr int NBY   = DIM / BY;        // 128 y-blocks
constexpr int NBZ   = DIM / CHUNK_Z;   // 32 z-blocks
constexpr int NWG   = NBY * NBZ;       // 4096
constexpr int NXCD  = 8;
constexpr int CHX   = NWG / NXCD;      // 512 blocks per XCD (bijective)

typedef float  nvec4  __attribute__((ext_vector_type(4)));
typedef int    nivec4 __attribute__((ext_vector_type(4)));
typedef float  v2f    __attribute__((ext_vector_type(2)));

struct f4p { v2f lo, hi; };            // 4 floats as two packed pairs

__device__ __forceinline__ v2f lo2(nvec4 v){ return __builtin_shufflevector(v, v, 0, 1); }
__device__ __forceinline__ v2f hi2(nvec4 v){ return __builtin_shufflevector(v, v, 2, 3); }
__device__ __forceinline__ f4p mkp(nvec4 v){ f4p r; r.lo = lo2(v); r.hi = hi2(v); return r; }

__device__ __forceinline__ float shlz(float v) {   // lane l <- lane l-1; lane0 -> 0
    float r = __shfl_up(v, 1);
    return (threadIdx.x == 0) ? 0.f : r;
}
__device__ __forceinline__ float shrz(float v) {   // lane l <- lane l+1; lane63 -> 0
    float r = __shfl_down(v, 1);
    return (threadIdx.x == 63) ? 0.f : r;
}

// packed helpers — per-element expression shape IDENTICAL to the scalar
// originals (add3: (a+b)+c; prod3: (a*b + c*d) + e*f), so contraction and
// bits are unchanged, just 2 elements per instruction.
__device__ __forceinline__ f4p add3p(const f4p& a, const f4p& b, const f4p& c) {
    f4p r; r.lo = a.lo + b.lo + c.lo; r.hi = a.hi + b.hi + c.hi; return r;
}
__device__ __forceinline__ f4p add2p(const f4p& a, const f4p& b) {
    f4p r; r.lo = a.lo + b.lo; r.hi = a.hi + b.hi; return r;
}
__device__ __forceinline__ f4p prod3p(const f4p& a, const f4p& b, const f4p& c,
                                      const f4p& d, const f4p& e, const f4p& f) {
    f4p r;
    r.lo = a.lo*b.lo + c.lo*d.lo + e.lo*f.lo;
    r.hi = a.hi*b.hi + c.hi*d.hi + e.hi*f.hi;
    return r;
}
__device__ __forceinline__ f4p sub4p(const f4p& a, const f4p& b) {
    f4p r; r.lo = a.lo - b.lo; r.hi = a.hi - b.hi; return r;
}
__device__ __forceinline__ f4p scl4p(const f4p& a, float s) {
    f4p r; r.lo = a.lo * s; r.hi = a.hi * s; return r;
}
// packed 3-wide x-window sum; element k: (left_k + c_k) + c_{k+1} — same
// association as the scalar xsum3.
__device__ __forceinline__ f4p xsum3p(const f4p& c, float l, float r) {
    const float c0 = c.lo.x, c1 = c.lo.y, c2 = c.hi.x, c3 = c.hi.y;
    v2f A = {l,  c0}, B = {c0, c1}, C = {c1, c2};
    v2f D = {c1, c2}, E = {c2, c3}, F = {c3, r};
    f4p o; o.lo = A + B + C; o.hi = D + E + F; return o;
}
__device__ __forceinline__ void ntstore4p(float* p, v2f lo, v2f hi) {
    nvec4 t = __builtin_shufflevector(lo, hi, 0, 1, 2, 3);
    __builtin_nontemporal_store(t, (nvec4*)p);
}

// packed pointwise NCC-force: 2 voxels per call. Expression shapes are
// op-for-op the scalar pw1 (absmax-80 tripwire) — do NOT reorder.
__device__ __forceinline__ void pw1p(
    v2f sum_m, v2f sum_f, v2f sum_mm, v2f sum_ff, v2f sum_mf,
    v2f mA, v2f mB, v2f mN,          // m at planes zo-1, zo, zo+1
    v2f fA, v2f fB, v2f fN,
    int zflag,                        // -1: zo==0, +1: zo==DIM-1, 0: interior
    v2f gx_m, v2f gy_m, v2f gx_f, v2f gy_f,
    int km0, int km1, int kf0, int kf1,
    v2f& o0, v2f& o1, v2f& o2)
{
    v2f mmean = sum_m / 27.0f;
    v2f fmean = sum_f / 27.0f;
    v2f var_m = sum_mm - 2.f*mmean*sum_m + 27.f*mmean*mmean;
    v2f var_f = sum_ff - 2.f*fmean*sum_f + 27.f*fmean*fmean;
    v2f var_mf = var_m * var_f;
    v2f cross = sum_mf - fmean*sum_m - mmean*sum_f + 27.f*mmean*fmean;
    v2f mmc = mB - mmean, fmc = fB - fmean;
    v2f factor = 2.f * cross / (var_mf + EPSF)
                 * (mmc - cross / (var_f*fmc + EPSF));
    v2f gzm = (zflag < 0) ? (mN - mB) : ((zflag > 0) ? (mB - mA) : 0.5f*(mN - mA));
    v2f gzf = (zflag < 0) ? (fN - fB) : ((zflag > 0) ? (fB - fA) : 0.5f*(fN - fA));
    v2f wm = { km0 ? 1.f : 0.f, km1 ? 1.f : 0.f };
    v2f wf = { kf0 ? 1.f : 0.f, kf1 ? 1.f : 0.f };
    v2f tgz = 0.5f*(gzm *wm + gzf *wf);
    v2f tgy = 0.5f*(gy_m*wm + gy_f*wf);
    v2f tgx = 0.5f*(gx_m*wm + gx_f*wf);
    o0 = -factor * tgz;
    o1 = -factor * tgy;
    o2 = -factor * tgx;
}

// raw rows of one z-plane for this wave's y (3 m-rows + 3 f-rows)
struct RawP { nvec4 mU, mC, mD, fU, fC, fD; };

__device__ __forceinline__ RawP load_planes(const float* __restrict__ M,
                                            const float* __restrict__ F,
                                            int zl, size_t yoff, bool yUok, bool yDok)
{
    const nvec4 z4 = {0.f, 0.f, 0.f, 0.f};
    RawP r; r.mU = z4; r.mC = z4; r.mD = z4; r.fU = z4; r.fC = z4; r.fD = z4;
    if ((unsigned)zl < (unsigned)DIM) {
        const float* pm = M + (size_t)zl * PLANE + yoff;
        const float* pf = F + (size_t)zl * PLANE + yoff;
        r.mC = *(const nvec4*)pm;  r.fC = *(const nvec4*)pf;
        if (yUok) { r.mU = *(const nvec4*)(pm - DIM); r.fU = *(const nvec4*)(pf - DIM); }
        if (yDok) { r.mD = *(const nvec4*)(pm + DIM); r.fD = *(const nvec4*)(pf + DIM); }
    }
    return r;
}

// compute half of the ingest — packed; FP statement order identical.
__device__ __forceinline__ void ingest_p(
    const RawP& r, int slot, int y,
    f4p* mc, f4p* fc,
    f4p& Pm, f4p& Pf, f4p& Pmm, f4p& Pff, f4p& Pmf,
    f4p& gxm, f4p& gym, f4p& gxf, f4p& gyf)
{
    const f4p mU = mkp(r.mU), mC = mkp(r.mC), mD = mkp(r.mD);
    const f4p fU = mkp(r.fU), fC = mkp(r.fC), fD = mkp(r.fD);
    // y-sums per element (zero-padded SAME)
    f4p Cm  = add3p(mU, mC, mD);
    f4p Cf  = add3p(fU, fC, fD);
    f4p Cmm = prod3p(mU, mU, mC, mC, mD, mD);
    f4p Cff = prod3p(fU, fU, fC, fC, fD, fD);
    f4p Cmf = prod3p(mU, fU, mC, fC, mD, fD);
    // x-sums (2 shuffles each)
    Pm  = xsum3p(Cm,  shlz(Cm.hi.y),  shrz(Cm.lo.x));
    Pf  = xsum3p(Cf,  shlz(Cf.hi.y),  shrz(Cf.lo.x));
    Pmm = xsum3p(Cmm, shlz(Cmm.hi.y), shrz(Cmm.lo.x));
    Pff = xsum3p(Cff, shlz(Cff.hi.y), shrz(Cff.lo.x));
    Pmf = xsum3p(Cmf, shlz(Cmf.hi.y), shrz(Cmf.lo.x));
    mc[slot] = mC; fc[slot] = fC;
    // in-plane gradients (torch.gradient boundary rules)
    const float m0 = mC.lo.x, m1 = mC.lo.y, m2 = mC.hi.x, m3 = mC.hi.y;
    const float f0 = fC.lo.x, f1 = fC.lo.y, f2 = fC.hi.x, f3 = fC.hi.y;
    float mL = shlz(m3), mR = shrz(m0);
    float fL = shlz(f3), fR = shrz(f0);
    gxm.lo = v2f{ (threadIdx.x == 0)  ? (m1 - m0) : 0.5f*(m1 - mL), 0.5f*(m2 - m0) };
    gxm.hi = v2f{ 0.5f*(m3 - m1), (threadIdx.x == 63) ? (m3 - m2) : 0.5f*(mR - m2) };
    gxf.lo = v2f{ (threadIdx.x == 0)  ? (f1 - f0) : 0.5f*(f1 - fL), 0.5f*(f2 - f0) };
    gxf.hi = v2f{ 0.5f*(f3 - f1), (threadIdx.x == 63) ? (f3 - f2) : 0.5f*(fR - f2) };
    gym = (y == 0) ? sub4p(mD, mC) : (y == DIM-1) ? sub4p(mC, mU) : scl4p(sub4p(mD, mU), 0.5f);
    gyf = (y == 0) ? sub4p(fD, fC) : (y == DIM-1) ? sub4p(fC, fU) : scl4p(sub4p(fD, fU), 0.5f);
}

__global__ __launch_bounds__(64 * BY) void ncc_forces(
    const float* __restrict__ M, const float* __restrict__ F,
    const int* __restrict__ maskM, const int* __restrict__ maskF,
    float* __restrict__ out)
{
    // XCD-aware bijective swizzle (kept: FETCH 225->135MB, R8)
    const int wg  = (int)blockIdx.x;
    const int swz = (wg & (NXCD - 1)) * CHX + (wg >> 3);
    const int by  = swz & (NBY - 1);
    const int bz  = swz >> 7;                       // NBY == 128

    const int y  = by * BY + threadIdx.y;
    const int z0 = bz * CHUNK_Z;
    const int xb = threadIdx.x * 4;
    const bool yUok = (y > 0), yDok = (y < DIM - 1);
    const size_t yoff = (size_t)y * DIM + xb;

    f4p mc[3], fc[3];                    // center values z-ring
    f4p gxm_p, gym_p, gxf_p, gyf_p;      // in-plane grads at output plane

    // ---- prologue: issue everything before the first compute ----
    nivec4 km = __builtin_nontemporal_load((const nivec4*)(maskM + (size_t)z0 * PLANE + yoff));
    nivec4 kf = __builtin_nontemporal_load((const nivec4*)(maskF + (size_t)z0 * PLANE + yoff));
    RawP r0 = load_planes(M, F, z0 - 1, yoff, yUok, yDok);
    RawP r1 = load_planes(M, F, z0,     yoff, yUok, yDok);
    RawP rN = load_planes(M, F, z0 + 1, yoff, yUok, yDok);   // consumed at s=2

    // pair-sum z-accumulators: SA = P(old)+P(mid), SB = P(mid)
    f4p SAm, SAf, SAmm, SAff, SAmf, SBm, SBf, SBmm, SBff, SBmf;
    {
        f4p P0m, P0f, P0mm, P0ff, P0mf, d0, d1, d2, d3;
        ingest_p(r0, 0, y, mc, fc, P0m, P0f, P0mm, P0ff, P0mf, d0, d1, d2, d3);
        f4p P1m, P1f, P1mm, P1ff, P1mf;
        ingest_p(r1, 1, y, mc, fc, P1m, P1f, P1mm, P1ff, P1mf,
                 gxm_p, gym_p, gxf_p, gyf_p);
        SAm  = add2p(P0m,  P1m );  SBm  = P1m;
        SAf  = add2p(P0f,  P1f );  SBf  = P1f;
        SAmm = add2p(P0mm, P1mm);  SBmm = P1mm;
        SAff = add2p(P0ff, P1ff);  SBff = P1ff;
        SAmf = add2p(P0mf, P1mf);  SBmf = P1mf;
    }

    #pragma unroll
    for (int s = 2; s < CHUNK_Z + 2; ++s) {
        const int i2 = s % 3, i1 = (s + 2) % 3, i0 = (s + 1) % 3;
        const int zo = z0 + s - 2;
        const int zflag = (zo == 0) ? -1 : ((zo == DIM - 1) ? 1 : 0);
        const size_t idx = (size_t)zo * PLANE + yoff;

        // 1) consume the raw loads issued one iteration ago
        f4p gxm, gym, gxf, gyf;
        f4p Pm2, Pf2, Pmm2, Pff2, Pmf2;
        ingest_p(rN, i2, y, mc, fc, Pm2, Pf2, Pmm2, Pff2, Pmf2,
                 gxm, gym, gxf, gyf);

        // 2) issue NEXT plane's raw rows and NEXT output's masks now
        nivec4 kmT, kfT;
        if (s < CHUNK_Z + 1) {
            rN  = load_planes(M, F, z0 + s, yoff, yUok, yDok);
            kmT = __builtin_nontemporal_load((const nivec4*)(maskM + idx + PLANE));
            kfT = __builtin_nontemporal_load((const nivec4*)(maskF + idx + PLANE));
        }

        // 3) z-sums: (P[z-2]+P[z-1]) + P[z] — identical association to add3
        f4p sm  = add2p(SAm,  Pm2);
        f4p sf  = add2p(SAf,  Pf2);
        f4p smm = add2p(SAmm, Pmm2);
        f4p sff = add2p(SAff, Pff2);
        f4p smf = add2p(SAmf, Pmf2);

        v2f o0l, o1l, o2l, o0h, o1h, o2h;
        pw1p(sm.lo, sf.lo, smm.lo, sff.lo, smf.lo,
             mc[i0].lo, mc[i1].lo, mc[i2].lo,
             fc[i0].lo, fc[i1].lo, fc[i2].lo, zflag,
             gxm_p.lo, gym_p.lo, gxf_p.lo, gyf_p.lo,
             km.x, km.y, kf.x, kf.y, o0l, o1l, o2l);
        pw1p(sm.hi, sf.hi, smm.hi, sff.hi, smf.hi,
             mc[i0].hi, mc[i1].hi, mc[i2].hi,
             fc[i0].hi, fc[i1].hi, fc[i2].hi, zflag,
             gxm_p.hi, gym_p.hi, gxf_p.hi, gyf_p.hi,
             km.z, km.w, kf.z, kf.w, o0h, o1h, o2h);

        ntstore4p(out + idx,            o0l, o0h);   // channel 0: d/dz
        ntstore4p(out + NVOX + idx,     o1l, o1h);   // channel 1: d/dy
        ntstore4p(out + 2 * NVOX + idx, o2l, o2h);   // channel 2: d/dx

        // 4) rotate accumulators / prefetch buffers
        SAm  = add2p(SBm,  Pm2 );  SBm  = Pm2;
        SAf  = add2p(SBf,  Pf2 );  SBf  = Pf2;
        SAmm = add2p(SBmm, Pmm2);  SBmm = Pmm2;
        SAff = add2p(SBff, Pff2);  SBff = Pff2;
        SAmf = add2p(SBmf, Pmf2);  SBmf = Pmf2;
        gxm_p = gxm; gym_p = gym; gxf_p = gxf; gyf_p = gyf;
        if (s < CHUNK_Z + 1) { km = kmT; kf = kfT; }
    }
}

extern "C" void kernel_launch(void* const* d_in, const int* in_sizes, int n_in,
                              void* d_out, int out_size, void* d_ws, size_t ws_size,
                              hipStream_t stream) {
    const float* M  = (const float*)d_in[0];
    const float* F  = (const float*)d_in[1];
    const int* mm   = (const int*)d_in[2];
    const int* fm   = (const int*)d_in[3];
    float* out      = (float*)d_out;

    dim3 block(64, BY, 1);                 // one wave = one full x-row
    dim3 grid(NWG, 1, 1);                  // flat 4096; (y,z) decoded in-kernel
    hipLaunchKernelGGL(ncc_forces, grid, block, 0, stream, M, F, mm, fm, out);
}